// Round 4
// baseline (36976.562 us; speedup 1.0000x reference)
//
#include <hip/hip_runtime.h>

typedef unsigned short u16;
typedef unsigned int u32;
typedef __attribute__((ext_vector_type(8))) short bf16x8;   // 8 x bf16 (4 VGPRs)
typedef __attribute__((ext_vector_type(4))) float f32x4;

#define NHID 850
#define BATCH 256
#define TSTEPS 128
#define KW 896        // K storage stride (850 valid + zero pad), 28 k-steps of 32
#define GRIDP 243     // 27 L0h + 7*27 node jobs + 54 dual jobs; 1 block/CU (115KB LDS)

#define ACT_SIG 0
#define ACT_TANH 1
#define ACT_RELU 2
#define ACT_ID 3

__device__ __forceinline__ u16 f2bf(float f) {
  u32 u = __float_as_uint(f);
  u32 r = (u + 0x7fffu + ((u >> 16) & 1u)) >> 16;   // RNE
  return (u16)r;
}
__device__ __forceinline__ float bf2f(u16 v) { return __uint_as_float(((u32)v) << 16); }
__device__ __forceinline__ float sigm(float x) { return 1.f / (1.f + __expf(-x)); }
__device__ __forceinline__ float act_apply(float x, int a) {
  if (a == ACT_SIG) return sigm(x);
  if (a == ACT_TANH) return 2.f * sigm(2.f * x) - 1.f;  // NaN-safe tanh
  if (a == ACT_RELU) return fmaxf(x, 0.f);
  return x;
}

#define GLOAD_LDS16(gsrc, ldst)                                                     \
  __builtin_amdgcn_global_load_lds((const __attribute__((address_space(1))) void*)(gsrc), \
                                   (__attribute__((address_space(3))) void*)(ldst), 16, 0, 0)

// ---------------------------------------------------------------- utility
__global__ void zero_kernel(uint4* p, u32 n) {
  u32 i = blockIdx.x * blockDim.x + threadIdx.x;
  const u32 stride = gridDim.x * blockDim.x;
  const uint4 z = {0u, 0u, 0u, 0u};
  for (; i < n; i += stride) p[i] = z;
}

// x (T,B,850) fp32 -> bf16 padded [T*B][896]; hidden (B,850) -> hb [B][896]
__global__ void convert_kernel(const float* __restrict__ x, const float* __restrict__ h0,
                               u16* __restrict__ xb, u16* __restrict__ hb) {
  const u32 NX = (u32)TSTEPS * BATCH * NHID;
  u32 i = blockIdx.x * blockDim.x + threadIdx.x;
  if (i < NX) {
    const u32 tb = i / NHID, j = i - tb * NHID;
    xb[(size_t)tb * KW + j] = f2bf(x[i]);
  } else if (i < NX + (u32)BATCH * NHID) {
    const u32 k = i - NX;
    const u32 b = k / NHID, j = k - b * NHID;
    hb[(size_t)b * KW + j] = f2bf(h0[k]);
  }
}

// Row mapping for the "quad-pair" N=64 job layout (fams 0..6 + w0x + xgemm decode):
//   output col n (0..1699): half = n>=850, q = n%850, jb = q/32, rem = q%32,
//   g = (rem/16)*2 + half, u = rem%16, r = jb*64 + g*16 + u.
// Frags then pair (c_q, h_q) at frags (0,1) and (2,3) on the SAME lane.
__device__ __forceinline__ int rmap64(int n) {
  const int half = (n >= NHID) ? 1 : 0;
  const int q = half ? (n - NHID) : n;
  const int rem = q & 31;
  return (q >> 5) * 64 + (((rem >> 4) << 1) | half) * 16 + (rem & 15);
}
// Dual-node N=32 layout (nodes 5 and 7): r = (q/16)*32 + half*16 + q%16.
__device__ __forceinline__ int rmap32(int n) {
  const int half = (n >= NHID) ? 1 : 0;
  const int q = half ? (n - NHID) : n;
  return (q >> 4) * 32 + half * 16 + (q & 15);
}

// ---------------------------------------------------------------- precompute (fp32)
// W0comb[m][n] = sum_r U[m][r]*sig[r]*V[r][n];  split by input dim m:
//   m<850 -> w0x[rmap64(n)][m] ; m>=850 -> w0h[rmap64(n)][m-850]   (both [1728][896] bf16)
__global__ __launch_bounds__(256) void prew0_kernel(const float* __restrict__ U,
                                                    const float* __restrict__ sig,
                                                    const float* __restrict__ V,
                                                    u16* __restrict__ w0x,
                                                    u16* __restrict__ w0h) {
  const int M = 1700, N = 1700, K = 1700;
  __shared__ float sA[64][17];
  __shared__ float sB[16][65];
  const int tid = threadIdx.x;
  const int tx = tid & 15, ty = tid >> 4;
  const int m0 = blockIdx.x * 64, n0 = blockIdx.y * 64;
  float acc[4][4] = {};
  for (int kb = 0; kb < K; kb += 16) {
#pragma unroll
    for (int i = 0; i < 4; ++i) {
      const int e = tid + i * 256;
      const int r = e >> 4, c = e & 15;
      const int mm = m0 + r, kk = kb + c;
      sA[r][c] = (mm < M && kk < K) ? U[(size_t)mm * K + kk] * sig[kk] : 0.f;
    }
#pragma unroll
    for (int i = 0; i < 4; ++i) {
      const int e = tid + i * 256;
      const int r = e >> 6, c = e & 63;
      const int kk = kb + r, nn = n0 + c;
      sB[r][c] = (kk < K && nn < N) ? V[(size_t)kk * N + nn] : 0.f;
    }
    __syncthreads();
#pragma unroll
    for (int k = 0; k < 16; ++k) {
      float a[4], b[4];
#pragma unroll
      for (int i = 0; i < 4; ++i) a[i] = sA[tx * 4 + i][k];
#pragma unroll
      for (int j = 0; j < 4; ++j) b[j] = sB[k][ty * 4 + j];
#pragma unroll
      for (int i = 0; i < 4; ++i)
#pragma unroll
        for (int j = 0; j < 4; ++j) acc[i][j] += a[i] * b[j];
    }
    __syncthreads();
  }
#pragma unroll
  for (int i = 0; i < 4; ++i) {
    const int m = m0 + tx * 4 + i;
    if (m >= M) continue;
#pragma unroll
    for (int j = 0; j < 4; ++j) {
      const int n = n0 + ty * 4 + j;
      if (n >= N) continue;
      const int r = rmap64(n);
      if (m < NHID) w0x[(size_t)r * KW + m] = f2bf(acc[i][j]);
      else w0h[(size_t)r * KW + (m - NHID)] = f2bf(acc[i][j]);
    }
  }
}

// per node i: Wcomb[m][n] = sum_r U_i[m][r]*sig_i[r]*V_i[r][n]
// nodes 5,7 use rmap32 (dual-job layout), others rmap64. Store wn[i][r][m].
__global__ __launch_bounds__(256) void prewn_kernel(const float* __restrict__ Uall,
                                                    const float* __restrict__ sigall,
                                                    const float* __restrict__ Vall,
                                                    u16* __restrict__ outBase) {
  const int M = 850, N = 1700, K = 850;
  const int ndi = blockIdx.z;
  const float* U = Uall + (size_t)ndi * 850 * 850;
  const float* sig = sigall + (size_t)ndi * 850;
  const float* V = Vall + (size_t)ndi * 1700 * 1700;
  u16* wn = outBase + (size_t)ndi * 1728 * KW;
  const bool dual = (ndi == 5 || ndi == 7);
  __shared__ float sA[64][17];
  __shared__ float sB[16][65];
  const int tid = threadIdx.x;
  const int tx = tid & 15, ty = tid >> 4;
  const int m0 = blockIdx.x * 64, n0 = blockIdx.y * 64;
  float acc[4][4] = {};
  for (int kb = 0; kb < K; kb += 16) {
#pragma unroll
    for (int i = 0; i < 4; ++i) {
      const int e = tid + i * 256;
      const int r = e >> 4, c = e & 15;
      const int mm = m0 + r, kk = kb + c;
      sA[r][c] = (mm < M && kk < K) ? U[(size_t)mm * K + kk] * sig[kk] : 0.f;
    }
#pragma unroll
    for (int i = 0; i < 4; ++i) {
      const int e = tid + i * 256;
      const int r = e >> 6, c = e & 63;
      const int kk = kb + r, nn = n0 + c;
      sB[r][c] = (kk < K && nn < N) ? V[(size_t)kk * 1700 + nn] : 0.f;
    }
    __syncthreads();
#pragma unroll
    for (int k = 0; k < 16; ++k) {
      float a[4], b[4];
#pragma unroll
      for (int i = 0; i < 4; ++i) a[i] = sA[tx * 4 + i][k];
#pragma unroll
      for (int j = 0; j < 4; ++j) b[j] = sB[k][ty * 4 + j];
#pragma unroll
      for (int i = 0; i < 4; ++i)
#pragma unroll
        for (int j = 0; j < 4; ++j) acc[i][j] += a[i] * b[j];
    }
    __syncthreads();
  }
#pragma unroll
  for (int i = 0; i < 4; ++i) {
    const int m = m0 + tx * 4 + i;
    if (m >= M) continue;
#pragma unroll
    for (int j = 0; j < 4; ++j) {
      const int n = n0 + ty * 4 + j;
      if (n >= N) continue;
      const int r = dual ? rmap32(n) : rmap64(n);
      wn[(size_t)r * KW + m] = f2bf(acc[i][j]);
    }
  }
}

// ---------------------------------------------------------------- xw0 = x @ W0x  (bf16 GEMM)
// Output stored into d_out slot t (bytes identical: 256*1700*2 == 256*850*4):
//   outU16[t*256*1700 + b*1700 + half*850 + j]
struct XArgs { const u16* A; const u16* B; u16* outU16; };

__global__ __launch_bounds__(256) void xgemm_kernel(XArgs xa) {
  __shared__ __align__(16) u16 lA[2][4096];
  __shared__ __align__(16) u16 lB[2][4096];
  const int tid = threadIdx.x;
  const int lane = tid & 63;
  const int w = tid >> 6;
  const int wm = (w & 1) * 32;
  const int wn = (w >> 1) * 32;
  const int m0 = blockIdx.x * 64;
  const int r0 = blockIdx.y * 64;
  f32x4 acc[2][2] = {};

  auto stage = [&](int buf, int kt) {
#pragma unroll
    for (int r2 = 0; r2 < 2; ++r2) {
      const int e = tid + 256 * r2;
      const int row = e >> 3;
      const int q = (e & 7) ^ (row & 7);
      GLOAD_LDS16(xa.A + (size_t)(m0 + row) * KW + kt * 64 + q * 8, &lA[buf][e * 8]);
      GLOAD_LDS16(xa.B + (size_t)(r0 + row) * KW + kt * 64 + q * 8, &lB[buf][e * 8]);
    }
  };

  stage(0, 0);
  int cur = 0;
  for (int kt = 0; kt < 14; ++kt) {
    __syncthreads();
    if (kt + 1 < 14) stage(cur ^ 1, kt + 1);
#pragma unroll
    for (int ks = 0; ks < 2; ++ks) {
      const int kg = lane >> 4;
      bf16x8 af[2], bb[2];
#pragma unroll
      for (int mf = 0; mf < 2; ++mf) {
        const int row = wm + mf * 16 + (lane & 15);
        const int p = (ks * 4 + kg) ^ (row & 7);
        af[mf] = *(const bf16x8*)&lA[cur][row * 64 + p * 8];
      }
#pragma unroll
      for (int nf = 0; nf < 2; ++nf) {
        const int nr = wn + nf * 16 + (lane & 15);
        const int p = (ks * 4 + kg) ^ (nr & 7);
        bb[nf] = *(const bf16x8*)&lB[cur][nr * 64 + p * 8];
      }
#pragma unroll
      for (int mf = 0; mf < 2; ++mf)
#pragma unroll
        for (int nf = 0; nf < 2; ++nf)
          acc[mf][nf] = __builtin_amdgcn_mfma_f32_16x16x32_bf16(af[mf], bb[nf], acc[mf][nf], 0, 0, 0);
    }
    cur ^= 1;
  }

  // C/D: col=lane&15, row=(lane>>4)*4+reg
  const int u = lane & 15, rb = (lane >> 4) << 2;
#pragma unroll
  for (int nf = 0; nf < 2; ++nf) {
    const int r = r0 + wn + nf * 16 + u;
    const int jb = r >> 6, rem = r & 63, g = rem >> 4, uu = rem & 15;
    const int half = g & 1;
    const int j = jb * 32 + (g >> 1) * 16 + uu;
    if (j >= NHID) continue;
#pragma unroll
    for (int mf = 0; mf < 2; ++mf) {
#pragma unroll
      for (int rr = 0; rr < 4; ++rr) {
        const int m = m0 + wm + mf * 16 + rb + rr;
        const int t = m >> 8, b = m & 255;
        xa.outU16[(size_t)t * BATCH * 1700 + b * 1700 + half * NHID + j] =
            f2bf(acc[mf][nf][rr]);
      }
    }
  }
}

// ---------------------------------------------------------------- persistent cell kernel
struct P2Args {
  const u16* wfam[7];   // fam0=w0h, fam1..4=wn0..3, fam5=wn4, fam6=wn6  ([1728][896])
  const u16* w5;        // wn5 (dual layout)
  const u16* w7;        // wn7 (dual layout)
  u16* hb;
  const float* h0;
  float* out;
  u16* outU16;
  float* sf[8];
  u16* sb[8];
  u32* bar;
};

// Relaxed-poll grid barrier (verified round 3): arrival=fetch_add(RELEASE),
// relaxed polls, one acquire fence at exit. Weights live in LDS so the
// acquire's L1/L2 invalidate no longer evicts them.
__device__ __forceinline__ void grid_sync(u32* cnt, u32 target) {
  __syncthreads();
  if (threadIdx.x == 0) {
    __hip_atomic_fetch_add(cnt, 1u, __ATOMIC_RELEASE, __HIP_MEMORY_SCOPE_AGENT);
    while (__hip_atomic_load(cnt, __ATOMIC_RELAXED, __HIP_MEMORY_SCOPE_AGENT) < target)
      __builtin_amdgcn_s_sleep(8);
    __builtin_amdgcn_fence(__ATOMIC_ACQUIRE, "agent");
  }
  __syncthreads();
}

// Core: acc[4mf][4nf] += A[256xK] x LDS-weights[64xK]^T, K=896 (28 k-steps).
// A-frag read direct global->VGPR in the m89-verified layout; B-frag from
// XOR-swizzled resident LDS (identical algebra to the verified staging kernel).
__device__ __forceinline__ void job_mfma(const u16* __restrict__ A, const u16* wl,
                                         f32x4 (&acc)[4][4]) {
  const int lane = threadIdx.x & 63;
  const int w = threadIdx.x >> 6;
  const int kg = lane >> 4;
  const int mbase = w * 64 + (lane & 15);
  const u16* ar[4];
#pragma unroll
  for (int mf = 0; mf < 4; ++mf) ar[mf] = A + (size_t)(mbase + mf * 16) * KW + kg * 8;
  bf16x8 a0[4], a1[4];
#pragma unroll
  for (int mf = 0; mf < 4; ++mf) a0[mf] = *(const bf16x8*)(ar[mf]);
#pragma unroll 2
  for (int s = 0; s < 28; ++s) {
    if (s < 27) {
#pragma unroll
      for (int mf = 0; mf < 4; ++mf) a1[mf] = *(const bf16x8*)(ar[mf] + (s + 1) * 32);
    }
    bf16x8 bb[4];
    const int kt = s >> 1, cb = (s & 1) * 4 + kg;
#pragma unroll
    for (int nf = 0; nf < 4; ++nf) {
      const int rr = nf * 16 + (lane & 15);
      bb[nf] = *(const bf16x8*)&wl[rr * KW + kt * 64 + ((cb ^ (rr & 7)) * 8)];
    }
#pragma unroll
    for (int mf = 0; mf < 4; ++mf)
#pragma unroll
      for (int nf = 0; nf < 4; ++nf)
        acc[mf][nf] = __builtin_amdgcn_mfma_f32_16x16x32_bf16(a0[mf], bb[nf], acc[mf][nf], 0, 0, 0);
#pragma unroll
    for (int mf = 0; mf < 4; ++mf) a0[mf] = a1[mf];
  }
}

// standard node epilogue: pairs (frag 2p = c_q, frag 2p+1 = h_q), j = jb*32+p*16+u
__device__ __forceinline__ void epi_std(const f32x4 (&acc)[4][4], int jb,
                                        const float* __restrict__ sp,
                                        float* __restrict__ outF, u16* __restrict__ outB,
                                        int act) {
  const int lane = threadIdx.x & 63, w = threadIdx.x >> 6;
  const int u = lane & 15, rb = (lane >> 4) << 2;
#pragma unroll
  for (int p = 0; p < 2; ++p) {
    const int j = jb * 32 + p * 16 + u;
    if (j >= NHID) continue;
#pragma unroll
    for (int mf = 0; mf < 4; ++mf) {
#pragma unroll
      for (int r = 0; r < 4; ++r) {
        const int m = w * 64 + mf * 16 + rb + r;
        const float cv = sigm(acc[mf][2 * p][r]);
        const float hv = act_apply(acc[mf][2 * p + 1][r], act);
        const float spv = sp[m * NHID + j];
        const float s = spv + cv * (hv - spv);
        outF[m * NHID + j] = s;
        outB[(size_t)m * KW + j] = f2bf(s);
      }
    }
  }
}

__global__ __launch_bounds__(256) void cell_persist2(P2Args pa) {
  __shared__ __align__(16) u16 wl[64 * KW];   // 114,688 B resident weights
  const int bx = blockIdx.x;
  const int tid = threadIdx.x;
  int fam, jb;
  if (bx < 189) { fam = bx / 27; jb = bx - fam * 27; }
  else { fam = 7; jb = bx - 189; }

  // ---- one-time weight fill (swizzle matches job_mfma's read)
  {
    const u16* s0;
    const u16* s1 = nullptr;
    if (fam < 7) s0 = pa.wfam[fam] + (size_t)jb * 64 * KW;
    else { s0 = pa.w5 + (size_t)jb * 32 * KW; s1 = pa.w7 + (size_t)jb * 32 * KW; }
    for (int idx = tid; idx < 64 * (KW / 8); idx += 256) {
      const int rr = idx / (KW / 8);
      const int cc = idx - rr * (KW / 8);
      const int kt = cc >> 3, c = cc & 7;
      const u16* srow = (s1 && rr >= 32) ? s1 + (size_t)(rr - 32) * KW
                                         : s0 + (size_t)rr * KW;
      const uint4 v = *(const uint4*)(srow + cc * 8);
      *(uint4*)&wl[rr * KW + kt * 64 + ((c ^ (rr & 7)) * 8)] = v;
    }
  }
  __syncthreads();

  u32 gen = 0;
  const u32 nb = gridDim.x;
  for (int t = 0; t < TSTEPS; ++t) {
    // ---- level 0: s0 = L0(x,h) ; x-part precomputed in d_out slot t
    if (fam == 0) {
      const float* hprev = (t == 0) ? pa.h0 : pa.out + (size_t)(t - 1) * BATCH * NHID;
      const u16* xw = pa.outU16 + (size_t)t * BATCH * 1700;
      f32x4 acc[4][4] = {};
      job_mfma(pa.hb, wl, acc);
      const int lane = tid & 63, w = tid >> 6;
      const int u = lane & 15, rb = (lane >> 4) << 2;
#pragma unroll
      for (int p = 0; p < 2; ++p) {
        const int j = jb * 32 + p * 16 + u;
        if (j >= NHID) continue;
#pragma unroll
        for (int mf = 0; mf < 4; ++mf) {
#pragma unroll
          for (int r = 0; r < 4; ++r) {
            const int m = w * 64 + mf * 16 + rb + r;
            const float xc = bf2f(xw[m * 1700 + j]);
            const float xh = bf2f(xw[m * 1700 + NHID + j]);
            const float cv = sigm(acc[mf][2 * p][r] + xc);
            const float hv = act_apply(acc[mf][2 * p + 1][r] + xh, ACT_TANH);
            const float spv = hprev[m * NHID + j];
            const float s = spv + cv * (hv - spv);
            pa.sf[0][m * NHID + j] = s;
            pa.sb[0][(size_t)m * KW + j] = f2bf(s);
          }
        }
      }
    }
    grid_sync(pa.bar, ++gen * nb);
    // ---- level 1: node0 (sigmoid, pred s0) -> s1
    if (fam == 1) {
      f32x4 acc[4][4] = {};
      job_mfma(pa.sb[0], wl, acc);
      epi_std(acc, jb, pa.sf[0], pa.sf[1], pa.sb[1], ACT_SIG);
    }
    grid_sync(pa.bar, ++gen * nb);
    // ---- level 2: nodes 1,2,3 (relu,relu,id, pred s1) -> s2,s3,s4
    if (fam >= 2 && fam <= 4) {
      f32x4 acc[4][4] = {};
      job_mfma(pa.sb[1], wl, acc);
      epi_std(acc, jb, pa.sf[1], pa.sf[fam], pa.sb[fam], (fam == 4) ? ACT_ID : ACT_RELU);
    }
    grid_sync(pa.bar, ++gen * nb);
    // ---- level 3: node4 (tanh, pred s2)->s5 ; node6 (tanh, pred s3)->s7
    if (fam == 5) {
      f32x4 acc[4][4] = {};
      job_mfma(pa.sb[2], wl, acc);
      epi_std(acc, jb, pa.sf[2], pa.sf[5], pa.sb[5], ACT_TANH);
    } else if (fam == 6) {
      f32x4 acc[4][4] = {};
      job_mfma(pa.sb[3], wl, acc);
      epi_std(acc, jb, pa.sf[3], pa.sf[7], pa.sb[7], ACT_TANH);
    }
    grid_sync(pa.bar, ++gen * nb);
    // ---- level 4: nodes 5(sig),7(relu) (both pred s5) + mean -> out[t], hb
    if (fam == 7) {
      f32x4 acc[4][4] = {};
      job_mfma(pa.sb[5], wl, acc);
      float* outH = pa.out + (size_t)t * BATCH * NHID;
      const int lane = tid & 63, w = tid >> 6;
      const int u = lane & 15, rb = (lane >> 4) << 2;
      const int j = jb * 16 + u;
      if (j < NHID) {
#pragma unroll
        for (int mf = 0; mf < 4; ++mf) {
#pragma unroll
          for (int r = 0; r < 4; ++r) {
            const int m = w * 64 + mf * 16 + rb + r;
            const int idx = m * NHID + j;
            const float s5v = pa.sf[5][idx];
            const float s6 = s5v + sigm(acc[mf][0][r]) * (sigm(acc[mf][1][r]) - s5v);
            const float s8 = s5v + sigm(acc[mf][2][r]) * (fmaxf(acc[mf][3][r], 0.f) - s5v);
            const float sum = pa.sf[1][idx] + pa.sf[2][idx] + pa.sf[3][idx] + pa.sf[4][idx]
                            + s5v + pa.sf[7][idx] + s6 + s8;
            const float h = sum * 0.125f;
            outH[idx] = h;                               // overwrites xw0 slot (already consumed)
            pa.hb[(size_t)m * KW + j] = f2bf(h);
          }
        }
      }
    }
    grid_sync(pa.bar, ++gen * nb);
  }
}

// ---------------------------------------------------------------- host
extern "C" void kernel_launch(void* const* d_in, const int* in_sizes, int n_in,
                              void* d_out, int out_size, void* d_ws, size_t ws_size,
                              hipStream_t stream) {
  const float* x = (const float*)d_in[0];
  const float* h0 = (const float*)d_in[1];
  const float* W0U = (const float*)d_in[2];
  const float* W0s = (const float*)d_in[3];
  const float* W0V = (const float*)d_in[4];
  const float* WsU = (const float*)d_in[5];
  const float* Wss = (const float*)d_in[6];
  const float* WsV = (const float*)d_in[7];
  float* out = (float*)d_out;
  char* ws = (char*)d_ws;

  const size_t SZ_W = (size_t)1728 * KW * 2;            // 3,096,576 per weight array
  const size_t OFF_W0X = 0;
  const size_t OFF_W0H = OFF_W0X + SZ_W;
  const size_t OFF_WN = OFF_W0H + SZ_W;                 // 8 node arrays
  const size_t OFF_XB = OFF_WN + 8 * SZ_W;
  const size_t SZ_XB = (size_t)TSTEPS * BATCH * KW * 2; // 58.7 MB
  const size_t OFF_HB = OFF_XB + SZ_XB;
  const size_t SZ_HB = (size_t)BATCH * KW * 2;
  const size_t OFF_SF = OFF_HB + SZ_HB;
  const size_t SZ_SF = (size_t)BATCH * NHID * 4;
  const size_t OFF_SB = OFF_SF + 8 * SZ_SF;
  const size_t SZ_SB = (size_t)BATCH * KW * 2;
  const size_t OFF_BAR = OFF_SB + 8 * SZ_SB;
  const size_t TOTAL = OFF_BAR + 128;                   // ~100.8 MB (round-1/3 used 103 MB OK)

  u16* w0x = (u16*)(ws + OFF_W0X);
  u16* w0h = (u16*)(ws + OFF_W0H);
  u16* wnBase = (u16*)(ws + OFF_WN);
  u16* xb = (u16*)(ws + OFF_XB);
  u16* hb = (u16*)(ws + OFF_HB);

  const size_t zbytes = (TOTAL <= ws_size) ? TOTAL : ws_size;
  zero_kernel<<<2048, 256, 0, stream>>>((uint4*)ws, (u32)((zbytes + 15) / 16));
  const u32 convTotal = (u32)TSTEPS * BATCH * NHID + (u32)BATCH * NHID;
  convert_kernel<<<(convTotal + 255) / 256, 256, 0, stream>>>(x, h0, xb, hb);
  prew0_kernel<<<dim3(27, 27), 256, 0, stream>>>(W0U, W0s, W0V, w0x, w0h);
  prewn_kernel<<<dim3(14, 27, 8), 256, 0, stream>>>(WsU, Wss, WsV, wnBase);

  XArgs xa;
  xa.A = xb;
  xa.B = w0x;
  xa.outU16 = (u16*)d_out;
  xgemm_kernel<<<dim3(TSTEPS * BATCH / 64, 27), 256, 0, stream>>>(xa);

  auto wn = [&](int i) { return wnBase + (size_t)i * 1728 * KW; };
  P2Args pa;
  pa.wfam[0] = w0h;
  pa.wfam[1] = wn(0); pa.wfam[2] = wn(1); pa.wfam[3] = wn(2); pa.wfam[4] = wn(3);
  pa.wfam[5] = wn(4); pa.wfam[6] = wn(6);
  pa.w5 = wn(5); pa.w7 = wn(7);
  pa.hb = hb;
  pa.h0 = h0;
  pa.out = out;
  pa.outU16 = (u16*)d_out;
  for (int i = 0; i < 8; ++i) {
    pa.sf[i] = (float*)(ws + OFF_SF + (size_t)i * SZ_SF);
    pa.sb[i] = (u16*)(ws + OFF_SB + (size_t)i * SZ_SB);
  }
  pa.bar = (u32*)(ws + OFF_BAR);

  cell_persist2<<<GRIDP, 256, 0, stream>>>(pa);

  hipMemcpyAsync(out + (size_t)TSTEPS * BATCH * NHID,
                 out + (size_t)(TSTEPS - 1) * BATCH * NHID,
                 (size_t)BATCH * NHID * sizeof(float), hipMemcpyDeviceToDevice, stream);
}